// Round 4
// baseline (904.091 us; speedup 1.0000x reference)
//
#include <hip/hip_runtime.h>

// Eikonal 2D: |grad u| = f, u(256,256)=0, Godunov upwind, converged fixed point.
//
// One wave (64 threads) per 32x32 tile; each thread holds a 4x4 cell block in
// registers. Per iteration: read 4 neighbor lines (LDS b128, or prefetched
// tile-halo registers), forward + backward in-register Gauss-Seidel sweeps
// (info moves 4 cells/iter in all directions), write own 4 edge lines to LDS,
// publish tile edges to packed d_ws arrays (agent scope; per-XCD L2s not
// coherent), single-wave __syncthreads (≈ waitcnt only). Tile halos are
// prefetched one iteration ahead -> LLC latency fully hidden.
// Monotone min-updates from BIG make every racy/stale read harmless (values
// only decrease, any schedule converges to the fixed point from above).
// Budget: thread-hop distance src->corner = 128, curvature ~1.6x + block-hop
// staleness ~32 + settle => ITERS=320 (safety margin ~1.25x).

#define NG    512
#define BIGV  1e10f
#define SRC   256
#define ITERS 320
#define WS_FLOATS 32768   // 4 halo arrays * 16*16*8 float4 * 4 floats = 128 KB

#define AL(p)    __hip_atomic_load((p),  __ATOMIC_RELAXED, __HIP_MEMORY_SCOPE_AGENT)
#define AS(p, x) __hip_atomic_store((p), (x), __ATOMIC_RELAXED, __HIP_MEMORY_SCOPE_AGENT)

__global__ void eik_ws_init(float* __restrict__ ws) {
    int idx = blockIdx.x * blockDim.x + threadIdx.x;
    if (idx < WS_FLOATS) ws[idx] = BIGV;
}

__global__ __launch_bounds__(64) void eik_persist(const float* __restrict__ f,
                                                  float* __restrict__ u,
                                                  float* __restrict__ ws) {
    // Per-thread edge lines, float4-packed: lane-contiguous b128, conflict-free.
    __shared__ float4 eTop[8][8], eBot[8][8], eLft[8][8], eRgt[8][8];  // 4 KB

    const int px = threadIdx.x, py = threadIdx.y;      // 8x8 threads
    const int TX = blockIdx.x,  TY = blockIdx.y;       // 16x16 tiles
    const int gi0 = TY * 32 + 4 * py;
    const int gj0 = TX * 32 + 4 * px;

    float v[4][4], fh[4][4], fh2[4][4];
#pragma unroll
    for (int r = 0; r < 4; ++r) {
        const float4 fr = *(const float4*)(f + (gi0 + r) * NG + gj0);
        fh[r][0] = fr.x; fh[r][1] = fr.y; fh[r][2] = fr.z; fh[r][3] = fr.w;
#pragma unroll
        for (int c = 0; c < 4; ++c) { fh2[r][c] = 2.0f * fh[r][c] * fh[r][c]; v[r][c] = BIGV; }
    }
    if (gi0 == SRC && gj0 == SRC) v[0][0] = 0.0f;   // source cell, kept 0 by fminf

    // packed tile-halo arrays in ws: [TY][TX][k] float4 lines
    float* wsTop = ws;
    float* wsBot = ws + 8192;
    float* wsLft = ws + 16384;
    float* wsRgt = ws + 24576;
#define WSO(T_y, T_x, k) ((((T_y) * 16 + (T_x)) * 8 + (k)) * 4)
    const bool ldU = (py == 0 && TY > 0),  ldD = (py == 7 && TY < 15);
    const bool ldL = (px == 0 && TX > 0),  ldR = (px == 7 && TX < 15);
    const float* pU = wsBot + WSO(TY - 1, TX, px);
    const float* pD = wsTop + WSO(TY + 1, TX, px);
    const float* pL = wsRgt + WSO(TY, TX - 1, py);
    const float* pR = wsLft + WSO(TY, TX + 1, py);
    float* sT = wsTop + WSO(TY, TX, px);
    float* sB = wsBot + WSO(TY, TX, px);
    float* sL = wsLft + WSO(TY, TX, py);
    float* sR = wsRgt + WSO(TY, TX, py);

    float hU[4], hD[4], hL[4], hR[4];   // prefetched tile halo (1 iter stale)
#pragma unroll
    for (int k = 0; k < 4; ++k) { hU[k] = hD[k] = hL[k] = hR[k] = BIGV; }

    const int pyu = py ? py - 1 : 0, pyd = (py < 7) ? py + 1 : 7;   // clamped
    const int pxl = px ? px - 1 : 0, pxr = (px < 7) ? px + 1 : 7;   // (discarded)

    eTop[py][px] = make_float4(v[0][0], v[0][1], v[0][2], v[0][3]);
    eBot[py][px] = make_float4(v[3][0], v[3][1], v[3][2], v[3][3]);
    eLft[py][px] = make_float4(v[0][0], v[1][0], v[2][0], v[3][0]);
    eRgt[py][px] = make_float4(v[0][3], v[1][3], v[2][3], v[3][3]);
    __syncthreads();

#define GOD(r, c, nu, nd, nl, nr) do {                                   \
        float a_  = fminf((nu), (nd));                                   \
        float b_  = fminf((nl), (nr));                                   \
        float d_  = fabsf(a_ - b_);                                      \
        float u1_ = fminf(a_, b_) + fh[r][c];                            \
        float t_  = fmaxf(fmaf(d_, -d_, fh2[r][c]), 0.0f);               \
        float u2_ = fmaf(0.5f, sqrtf(t_), 0.5f * (a_ + b_));             \
        float un_ = (d_ >= fh[r][c]) ? u1_ : u2_;                        \
        v[r][c] = fminf(v[r][c], un_);                                   \
    } while (0)

    for (int it = 0; it < ITERS; ++it) {
        // neighbor lines: LDS (prev iter) or prefetched tile halo
        float4 u4 = eBot[pyu][px];
        float4 d4 = eTop[pyd][px];
        float4 l4 = eRgt[py][pxl];
        float4 r4 = eLft[py][pxr];
        float up[4] = { py == 0 ? hU[0] : u4.x, py == 0 ? hU[1] : u4.y,
                        py == 0 ? hU[2] : u4.z, py == 0 ? hU[3] : u4.w };
        float dn[4] = { py == 7 ? hD[0] : d4.x, py == 7 ? hD[1] : d4.y,
                        py == 7 ? hD[2] : d4.z, py == 7 ? hD[3] : d4.w };
        float lf[4] = { px == 0 ? hL[0] : l4.x, px == 0 ? hL[1] : l4.y,
                        px == 0 ? hL[2] : l4.z, px == 0 ? hL[3] : l4.w };
        float rt[4] = { px == 7 ? hR[0] : r4.x, px == 7 ? hR[1] : r4.y,
                        px == 7 ? hR[2] : r4.z, px == 7 ? hR[3] : r4.w };

        // prefetch next tile halo (consumed next iteration -> latency hidden)
        if (ldU) { hU[0] = AL(pU + 0); hU[1] = AL(pU + 1); hU[2] = AL(pU + 2); hU[3] = AL(pU + 3); }
        if (ldD) { hD[0] = AL(pD + 0); hD[1] = AL(pD + 1); hD[2] = AL(pD + 2); hD[3] = AL(pD + 3); }
        if (ldL) { hL[0] = AL(pL + 0); hL[1] = AL(pL + 1); hL[2] = AL(pL + 2); hL[3] = AL(pL + 3); }
        if (ldR) { hR[0] = AL(pR + 0); hR[1] = AL(pR + 1); hR[2] = AL(pR + 2); hR[3] = AL(pR + 3); }

        // forward sweep (down/right fast)
#pragma unroll
        for (int r = 0; r < 4; ++r)
#pragma unroll
            for (int c = 0; c < 4; ++c) {
                float nu = (r == 0) ? up[c] : v[r - 1][c];
                float nd = (r == 3) ? dn[c] : v[r + 1][c];
                float nl = (c == 0) ? lf[r] : v[r][c - 1];
                float nr = (c == 3) ? rt[r] : v[r][c + 1];
                GOD(r, c, nu, nd, nl, nr);
            }
        // backward sweep (up/left fast)
#pragma unroll
        for (int r = 3; r >= 0; --r)
#pragma unroll
            for (int c = 3; c >= 0; --c) {
                float nu = (r == 0) ? up[c] : v[r - 1][c];
                float nd = (r == 3) ? dn[c] : v[r + 1][c];
                float nl = (c == 0) ? lf[r] : v[r][c - 1];
                float nr = (c == 3) ? rt[r] : v[r][c + 1];
                GOD(r, c, nu, nd, nl, nr);
            }

        // publish edge lines (LDS for intra-tile, ws for inter-tile)
        eTop[py][px] = make_float4(v[0][0], v[0][1], v[0][2], v[0][3]);
        eBot[py][px] = make_float4(v[3][0], v[3][1], v[3][2], v[3][3]);
        eLft[py][px] = make_float4(v[0][0], v[1][0], v[2][0], v[3][0]);
        eRgt[py][px] = make_float4(v[0][3], v[1][3], v[2][3], v[3][3]);
        if (py == 0) { AS(sT + 0, v[0][0]); AS(sT + 1, v[0][1]); AS(sT + 2, v[0][2]); AS(sT + 3, v[0][3]); }
        if (py == 7) { AS(sB + 0, v[3][0]); AS(sB + 1, v[3][1]); AS(sB + 2, v[3][2]); AS(sB + 3, v[3][3]); }
        if (px == 0) { AS(sL + 0, v[0][0]); AS(sL + 1, v[1][0]); AS(sL + 2, v[2][0]); AS(sL + 3, v[3][0]); }
        if (px == 7) { AS(sR + 0, v[0][3]); AS(sR + 1, v[1][3]); AS(sR + 2, v[2][3]); AS(sR + 3, v[3][3]); }
        __syncthreads();   // single wave: compiles to waitcnt (+cheap barrier)
    }

#pragma unroll
    for (int r = 0; r < 4; ++r)
        *(float4*)(u + (gi0 + r) * NG + gj0) = make_float4(v[r][0], v[r][1], v[r][2], v[r][3]);
#undef GOD
#undef WSO
}

extern "C" void kernel_launch(void* const* d_in, const int* in_sizes, int n_in,
                              void* d_out, int out_size, void* d_ws, size_t ws_size,
                              hipStream_t stream) {
    const float* f = (const float*)d_in[0];
    float* u  = (float*)d_out;
    float* ws = (float*)d_ws;   // 128 KB packed tile-halo exchange buffers

    eik_ws_init<<<WS_FLOATS / 256, 256, 0, stream>>>(ws);

    dim3 grid(16, 16);     // one 32x32 tile per block, 256 blocks (1/CU)
    dim3 block(8, 8);      // 64 threads = 1 wave, 4x4 cells/thread
    eik_persist<<<grid, block, 0, stream>>>(f, u, ws);
}

// Round 5
// 903.940 us; speedup vs baseline: 1.0002x; 1.0002x over previous
//
#include <hip/hip_runtime.h>

// Eikonal 2D: |grad u| = f, u(256,256)=0, Godunov upwind, converged fixed point.
//
// One wave (64 threads) per 32x32 tile; each thread holds a 4x4 cell block in
// registers. Per iteration: read 4 neighbor lines (LDS b128, or tile-halo regs
// prefetched LAST iteration), forward + backward in-register Gauss-Seidel
// sweeps (info moves 4 cells/iter in all directions), write own 4 edge lines
// to LDS, publish tile edges to packed d_ws arrays (agent scope; per-XCD L2s
// not coherent). KEY CHANGE vs R4: the block is a single wave, so there is NO
// __syncthreads in the loop — only `s_waitcnt lgkmcnt(0)` (inline asm, memory
// clobber). This preserves LDS write->read ordering but never forces
// vmcnt(0), so agent-scope halo stores are fire-and-forget and halo loads are
// consumed one full iteration after issue (LLC latency hidden). R4's
// __syncthreads drained vmcnt every iteration -> 6470 cyc/iter, 85% stall.
// Monotone min-updates from BIG make every racy/stale read harmless (values
// only decrease; any schedule converges to the fixed point from above).
// Budget: chebyshev distance src->corner = 256 cells @ 4 cells/iter = 64, x
// curvature ~1.6 + ~2-iter staleness per tile crossing (~16) + settle =>
// ITERS=320 carried from R4 (passed at absmax 2.0 = bf16 floor).

#define NG    512
#define BIGV  1e10f
#define SRC   256
#define ITERS 320
#define WS_FLOATS 32768   // 4 halo arrays * 16*16 tiles * 8 float4 = 128 KB

#define AL(p)    __hip_atomic_load((p),  __ATOMIC_RELAXED, __HIP_MEMORY_SCOPE_AGENT)
#define AS(p, x) __hip_atomic_store((p), (x), __ATOMIC_RELAXED, __HIP_MEMORY_SCOPE_AGENT)
// single-wave "barrier": order LDS ops, never touch vmcnt
#define WAVE_LDS_SYNC() __asm__ volatile("s_waitcnt lgkmcnt(0)" ::: "memory")

__global__ void eik_ws_init(float* __restrict__ ws) {
    int idx = blockIdx.x * blockDim.x + threadIdx.x;
    if (idx < WS_FLOATS) ws[idx] = BIGV;
}

__global__ __launch_bounds__(64) void eik_persist(const float* __restrict__ f,
                                                  float* __restrict__ u,
                                                  float* __restrict__ ws) {
    // Per-thread edge lines, float4-packed: lane-contiguous b128 access.
    __shared__ float4 eTop[8][8], eBot[8][8], eLft[8][8], eRgt[8][8];  // 4 KB

    const int px = threadIdx.x, py = threadIdx.y;      // 8x8 threads
    const int TX = blockIdx.x,  TY = blockIdx.y;       // 16x16 tiles
    const int gi0 = TY * 32 + 4 * py;
    const int gj0 = TX * 32 + 4 * px;

    float v[4][4], fh[4][4], fh2[4][4];
#pragma unroll
    for (int r = 0; r < 4; ++r) {
        const float4 fr = *(const float4*)(f + (gi0 + r) * NG + gj0);
        fh[r][0] = fr.x; fh[r][1] = fr.y; fh[r][2] = fr.z; fh[r][3] = fr.w;
#pragma unroll
        for (int c = 0; c < 4; ++c) { fh2[r][c] = 2.0f * fh[r][c] * fh[r][c]; v[r][c] = BIGV; }
    }
    if (gi0 == SRC && gj0 == SRC) v[0][0] = 0.0f;   // source cell, kept 0 by fminf

    // packed tile-halo arrays in ws: [TY][TX][k] float4 lines
    float* wsTop = ws;
    float* wsBot = ws + 8192;
    float* wsLft = ws + 16384;
    float* wsRgt = ws + 24576;
#define WSO(T_y, T_x, k) ((((T_y) * 16 + (T_x)) * 8 + (k)) * 4)
    const bool ldU = (py == 0 && TY > 0),  ldD = (py == 7 && TY < 15);
    const bool ldL = (px == 0 && TX > 0),  ldR = (px == 7 && TX < 15);
    const float* pU = wsBot + WSO(TY - 1, TX, px);
    const float* pD = wsTop + WSO(TY + 1, TX, px);
    const float* pL = wsRgt + WSO(TY, TX - 1, py);
    const float* pR = wsLft + WSO(TY, TX + 1, py);
    float* sT = wsTop + WSO(TY, TX, px);
    float* sB = wsBot + WSO(TY, TX, px);
    float* sL = wsLft + WSO(TY, TX, py);
    float* sR = wsRgt + WSO(TY, TX, py);

    float hU[4], hD[4], hL[4], hR[4];   // tile halo, prefetched 1 iter ahead
#pragma unroll
    for (int k = 0; k < 4; ++k) { hU[k] = hD[k] = hL[k] = hR[k] = BIGV; }

    const int pyu = py ? py - 1 : 0, pyd = (py < 7) ? py + 1 : 7;   // clamped
    const int pxl = px ? px - 1 : 0, pxr = (px < 7) ? px + 1 : 7;   // (discarded)

    eTop[py][px] = make_float4(v[0][0], v[0][1], v[0][2], v[0][3]);
    eBot[py][px] = make_float4(v[3][0], v[3][1], v[3][2], v[3][3]);
    eLft[py][px] = make_float4(v[0][0], v[1][0], v[2][0], v[3][0]);
    eRgt[py][px] = make_float4(v[0][3], v[1][3], v[2][3], v[3][3]);
    __syncthreads();   // once, before the loop

#define GOD(r, c, nu, nd, nl, nr) do {                                   \
        float a_  = fminf((nu), (nd));                                   \
        float b_  = fminf((nl), (nr));                                   \
        float d_  = fabsf(a_ - b_);                                      \
        float u1_ = fminf(a_, b_) + fh[r][c];                            \
        float t_  = fmaxf(fmaf(d_, -d_, fh2[r][c]), 0.0f);               \
        float u2_ = fmaf(0.5f, sqrtf(t_), 0.5f * (a_ + b_));             \
        float un_ = (d_ >= fh[r][c]) ? u1_ : u2_;                        \
        v[r][c] = fminf(v[r][c], un_);                                   \
    } while (0)

    for (int it = 0; it < ITERS; ++it) {
        // neighbor lines from LDS (published last iteration)
        float4 u4 = eBot[pyu][px];
        float4 d4 = eTop[pyd][px];
        float4 l4 = eRgt[py][pxl];
        float4 r4 = eLft[py][pxr];
        // consume the halo regs (loaded LAST iteration; vmcnt wait lands here,
        // ~1 full iteration after issue -> LLC latency hidden)
        float up[4] = { py == 0 ? hU[0] : u4.x, py == 0 ? hU[1] : u4.y,
                        py == 0 ? hU[2] : u4.z, py == 0 ? hU[3] : u4.w };
        float dn[4] = { py == 7 ? hD[0] : d4.x, py == 7 ? hD[1] : d4.y,
                        py == 7 ? hD[2] : d4.z, py == 7 ? hD[3] : d4.w };
        float lf[4] = { px == 0 ? hL[0] : l4.x, px == 0 ? hL[1] : l4.y,
                        px == 0 ? hL[2] : l4.z, px == 0 ? hL[3] : l4.w };
        float rt[4] = { px == 7 ? hR[0] : r4.x, px == 7 ? hR[1] : r4.y,
                        px == 7 ? hR[2] : r4.z, px == 7 ? hR[3] : r4.w };

        // issue next iteration's halo loads (no wait until next consume)
        if (ldU) { hU[0] = AL(pU + 0); hU[1] = AL(pU + 1); hU[2] = AL(pU + 2); hU[3] = AL(pU + 3); }
        if (ldD) { hD[0] = AL(pD + 0); hD[1] = AL(pD + 1); hD[2] = AL(pD + 2); hD[3] = AL(pD + 3); }
        if (ldL) { hL[0] = AL(pL + 0); hL[1] = AL(pL + 1); hL[2] = AL(pL + 2); hL[3] = AL(pL + 3); }
        if (ldR) { hR[0] = AL(pR + 0); hR[1] = AL(pR + 1); hR[2] = AL(pR + 2); hR[3] = AL(pR + 3); }

        // forward sweep (down/right fast)
#pragma unroll
        for (int r = 0; r < 4; ++r)
#pragma unroll
            for (int c = 0; c < 4; ++c) {
                float nu = (r == 0) ? up[c] : v[r - 1][c];
                float nd = (r == 3) ? dn[c] : v[r + 1][c];
                float nl = (c == 0) ? lf[r] : v[r][c - 1];
                float nr = (c == 3) ? rt[r] : v[r][c + 1];
                GOD(r, c, nu, nd, nl, nr);
            }
        // backward sweep (up/left fast)
#pragma unroll
        for (int r = 3; r >= 0; --r)
#pragma unroll
            for (int c = 3; c >= 0; --c) {
                float nu = (r == 0) ? up[c] : v[r - 1][c];
                float nd = (r == 3) ? dn[c] : v[r + 1][c];
                float nl = (c == 0) ? lf[r] : v[r][c - 1];
                float nr = (c == 3) ? rt[r] : v[r][c + 1];
                GOD(r, c, nu, nd, nl, nr);
            }

        // publish edge lines: LDS for intra-tile, ws (fire-and-forget agent
        // stores, never drained) for inter-tile
        eTop[py][px] = make_float4(v[0][0], v[0][1], v[0][2], v[0][3]);
        eBot[py][px] = make_float4(v[3][0], v[3][1], v[3][2], v[3][3]);
        eLft[py][px] = make_float4(v[0][0], v[1][0], v[2][0], v[3][0]);
        eRgt[py][px] = make_float4(v[0][3], v[1][3], v[2][3], v[3][3]);
        if (py == 0) { AS(sT + 0, v[0][0]); AS(sT + 1, v[0][1]); AS(sT + 2, v[0][2]); AS(sT + 3, v[0][3]); }
        if (py == 7) { AS(sB + 0, v[3][0]); AS(sB + 1, v[3][1]); AS(sB + 2, v[3][2]); AS(sB + 3, v[3][3]); }
        if (px == 0) { AS(sL + 0, v[0][0]); AS(sL + 1, v[1][0]); AS(sL + 2, v[2][0]); AS(sL + 3, v[3][0]); }
        if (px == 7) { AS(sR + 0, v[0][3]); AS(sR + 1, v[1][3]); AS(sR + 2, v[2][3]); AS(sR + 3, v[3][3]); }

        WAVE_LDS_SYNC();   // single wave: LDS ordering only, vmcnt untouched
    }

#pragma unroll
    for (int r = 0; r < 4; ++r)
        *(float4*)(u + (gi0 + r) * NG + gj0) = make_float4(v[r][0], v[r][1], v[r][2], v[r][3]);
#undef GOD
#undef WSO
}

extern "C" void kernel_launch(void* const* d_in, const int* in_sizes, int n_in,
                              void* d_out, int out_size, void* d_ws, size_t ws_size,
                              hipStream_t stream) {
    const float* f = (const float*)d_in[0];
    float* u  = (float*)d_out;
    float* ws = (float*)d_ws;   // 128 KB packed tile-halo exchange buffers

    eik_ws_init<<<WS_FLOATS / 256, 256, 0, stream>>>(ws);

    dim3 grid(16, 16);     // one 32x32 tile per block, 256 blocks (1/CU)
    dim3 block(8, 8);      // 64 threads = 1 wave, 4x4 cells/thread
    eik_persist<<<grid, block, 0, stream>>>(f, u, ws);
}